// Round 3
// baseline (6117.901 us; speedup 1.0000x reference)
//
#include <hip/hip_runtime.h>
#include <cstdint>
#include <cstddef>

// ---------------------------------------------------------------------------
// Net_25950192402497: 2-layer MLP-message GNN + link-prediction head.
// Identity: segment_sum(concat(x_i,x_j,ef)@W + b) over dst
//   = deg*(h@Wi + b) + (gather-sum h[src])@Wj + (gather-sum ef)@We
// R3: (a) 3-phase parallel scan (R2's single-block scan was 148us @0.045%
// occupancy); (b) fuse the 3 message GEMMs (K=128+128+16) into one kernel
// with dual accumulators, killing 2 RMW passes over C.
// ---------------------------------------------------------------------------

// Pre-conv GEMM: OUT[r,0:128] = relu(X[r,0:128] @ W[128,128] + bias)
__launch_bounds__(256)
__global__ void gemm_tiled(const float* __restrict__ X, const float* __restrict__ W,
                           const float* __restrict__ bias, float* __restrict__ OUT,
                           int Nrows)
{
    __shared__ float ws[64 * 128];   // 32 KB: K-tile of W
    __shared__ float xs[32 * 128];   // 16 KB: 32 staged input rows
    const int tid = threadIdx.x;
    const int c  = tid & 31;         // column quad: cols 4c..4c+3
    const int rg = tid >> 5;         // row group: rows 4rg..4rg+3
    const int row0 = blockIdx.x << 5;

    for (int idx = tid; idx < 32 * 128; idx += 256) {
        const int r = idx >> 7;
        const int k = idx & 127;
        const int gr = row0 + r;
        xs[idx] = (gr < Nrows) ? X[((size_t)gr << 7) + k] : 0.0f;
    }

    float acc[4][4];
#pragma unroll
    for (int i = 0; i < 4; ++i)
#pragma unroll
        for (int j = 0; j < 4; ++j) acc[i][j] = 0.0f;

    for (int kt = 0; kt < 128; kt += 64) {
        __syncthreads();
        for (int idx = tid; idx < 64 * 128; idx += 256)
            ws[idx] = W[((size_t)kt << 7) + idx];
        __syncthreads();
        for (int k = 0; k < 64; k += 4) {
            const float4 w0 = *(const float4*)&ws[((k + 0) << 7) + (c << 2)];
            const float4 w1 = *(const float4*)&ws[((k + 1) << 7) + (c << 2)];
            const float4 w2 = *(const float4*)&ws[((k + 2) << 7) + (c << 2)];
            const float4 w3 = *(const float4*)&ws[((k + 3) << 7) + (c << 2)];
#pragma unroll
            for (int i = 0; i < 4; ++i) {
                const int r = (rg << 2) + i;
                const float4 xq = *(const float4*)&xs[(r << 7) + kt + k];
                acc[i][0] += xq.x * w0.x + xq.y * w1.x + xq.z * w2.x + xq.w * w3.x;
                acc[i][1] += xq.x * w0.y + xq.y * w1.y + xq.z * w2.y + xq.w * w3.y;
                acc[i][2] += xq.x * w0.z + xq.y * w1.z + xq.z * w2.z + xq.w * w3.z;
                acc[i][3] += xq.x * w0.w + xq.y * w1.w + xq.z * w2.w + xq.w * w3.w;
            }
        }
    }

#pragma unroll
    for (int i = 0; i < 4; ++i) {
        const int r = row0 + (rg << 2) + i;
        if (r >= Nrows) continue;
        const float4 bq = *(const float4*)&bias[c << 2];
        float4 v = make_float4(fmaxf(acc[i][0] + bq.x, 0.f),
                               fmaxf(acc[i][1] + bq.y, 0.f),
                               fmaxf(acc[i][2] + bq.z, 0.f),
                               fmaxf(acc[i][3] + bq.w, 0.f));
        *(float4*)(OUT + ((size_t)r << 7) + (c << 2)) = v;
    }
}

// Fused message GEMM: OUT[r] = act( deg[r]*(A[r]@Wi + b) + B[r]@Wj + EFA[r]@We )
// W laid out rows 0..127 = Wi, 128..255 = Wj, 256..271 = We (shape 272x128).
__launch_bounds__(256)
__global__ void fused_msg(const float* __restrict__ A, const float* __restrict__ B,
                          const float* __restrict__ EFA, const float* __restrict__ DEG,
                          const float* __restrict__ W, const float* __restrict__ bias,
                          float* __restrict__ OUT, int Nrows, int relu)
{
    __shared__ float ws[64 * 128];   // 32 KB
    __shared__ float xsA[32 * 128];  // 16 KB
    __shared__ float xsB[32 * 128];  // 16 KB
    __shared__ float xsE[32 * 16];   // 2 KB
    const int tid = threadIdx.x;
    const int c  = tid & 31;
    const int rg = tid >> 5;
    const int row0 = blockIdx.x << 5;

    for (int idx = tid; idx < 32 * 128; idx += 256) {
        const int r = idx >> 7;
        const int k = idx & 127;
        const int gr = row0 + r;
        const bool ok = gr < Nrows;
        xsA[idx] = ok ? A[((size_t)gr << 7) + k] : 0.0f;
        xsB[idx] = ok ? B[((size_t)gr << 7) + k] : 0.0f;
    }
    for (int idx = tid; idx < 32 * 16; idx += 256) {
        const int r = idx >> 4;
        const int k = idx & 15;
        const int gr = row0 + r;
        xsE[idx] = (gr < Nrows) ? EFA[((size_t)gr << 4) + k] : 0.0f;
    }

    float acc_i[4][4], acc_r[4][4];
#pragma unroll
    for (int i = 0; i < 4; ++i)
#pragma unroll
        for (int j = 0; j < 4; ++j) { acc_i[i][j] = 0.0f; acc_r[i][j] = 0.0f; }

    // ---- Wi (rows 0..127) into acc_i, X = xsA ----
#pragma unroll
    for (int half = 0; half < 2; ++half) {
        const int kt = half << 6;
        __syncthreads();
        for (int idx = tid; idx < 64 * 128; idx += 256)
            ws[idx] = W[((size_t)kt << 7) + idx];
        __syncthreads();
        for (int k = 0; k < 64; k += 4) {
            const float4 w0 = *(const float4*)&ws[((k + 0) << 7) + (c << 2)];
            const float4 w1 = *(const float4*)&ws[((k + 1) << 7) + (c << 2)];
            const float4 w2 = *(const float4*)&ws[((k + 2) << 7) + (c << 2)];
            const float4 w3 = *(const float4*)&ws[((k + 3) << 7) + (c << 2)];
#pragma unroll
            for (int i = 0; i < 4; ++i) {
                const int r = (rg << 2) + i;
                const float4 xq = *(const float4*)&xsA[(r << 7) + kt + k];
                acc_i[i][0] += xq.x * w0.x + xq.y * w1.x + xq.z * w2.x + xq.w * w3.x;
                acc_i[i][1] += xq.x * w0.y + xq.y * w1.y + xq.z * w2.y + xq.w * w3.y;
                acc_i[i][2] += xq.x * w0.z + xq.y * w1.z + xq.z * w2.z + xq.w * w3.z;
                acc_i[i][3] += xq.x * w0.w + xq.y * w1.w + xq.z * w2.w + xq.w * w3.w;
            }
        }
    }

    // ---- Wj (rows 128..255) into acc_r, X = xsB ----
#pragma unroll
    for (int half = 0; half < 2; ++half) {
        const int kt = half << 6;
        __syncthreads();
        for (int idx = tid; idx < 64 * 128; idx += 256)
            ws[idx] = W[((size_t)(128 + kt) << 7) + idx];
        __syncthreads();
        for (int k = 0; k < 64; k += 4) {
            const float4 w0 = *(const float4*)&ws[((k + 0) << 7) + (c << 2)];
            const float4 w1 = *(const float4*)&ws[((k + 1) << 7) + (c << 2)];
            const float4 w2 = *(const float4*)&ws[((k + 2) << 7) + (c << 2)];
            const float4 w3 = *(const float4*)&ws[((k + 3) << 7) + (c << 2)];
#pragma unroll
            for (int i = 0; i < 4; ++i) {
                const int r = (rg << 2) + i;
                const float4 xq = *(const float4*)&xsB[(r << 7) + kt + k];
                acc_r[i][0] += xq.x * w0.x + xq.y * w1.x + xq.z * w2.x + xq.w * w3.x;
                acc_r[i][1] += xq.x * w0.y + xq.y * w1.y + xq.z * w2.y + xq.w * w3.y;
                acc_r[i][2] += xq.x * w0.z + xq.y * w1.z + xq.z * w2.z + xq.w * w3.z;
                acc_r[i][3] += xq.x * w0.w + xq.y * w1.w + xq.z * w2.w + xq.w * w3.w;
            }
        }
    }

    // ---- We (rows 256..271, K=16) into acc_r, X = xsE ----
    __syncthreads();
    for (int idx = tid; idx < 16 * 128; idx += 256)
        ws[idx] = W[((size_t)256 << 7) + idx];
    __syncthreads();
    for (int k = 0; k < 16; k += 4) {
        const float4 w0 = *(const float4*)&ws[((k + 0) << 7) + (c << 2)];
        const float4 w1 = *(const float4*)&ws[((k + 1) << 7) + (c << 2)];
        const float4 w2 = *(const float4*)&ws[((k + 2) << 7) + (c << 2)];
        const float4 w3 = *(const float4*)&ws[((k + 3) << 7) + (c << 2)];
#pragma unroll
        for (int i = 0; i < 4; ++i) {
            const int r = (rg << 2) + i;
            const float4 xq = *(const float4*)&xsE[(r << 4) + k];
            acc_r[i][0] += xq.x * w0.x + xq.y * w1.x + xq.z * w2.x + xq.w * w3.x;
            acc_r[i][1] += xq.x * w0.y + xq.y * w1.y + xq.z * w2.y + xq.w * w3.y;
            acc_r[i][2] += xq.x * w0.z + xq.y * w1.z + xq.z * w2.z + xq.w * w3.z;
            acc_r[i][3] += xq.x * w0.w + xq.y * w1.w + xq.z * w2.w + xq.w * w3.w;
        }
    }

#pragma unroll
    for (int i = 0; i < 4; ++i) {
        const int r = row0 + (rg << 2) + i;
        if (r >= Nrows) continue;
        const float s = DEG[r];
        const float4 bq = *(const float4*)&bias[c << 2];
        float4 v = make_float4(s * (acc_i[i][0] + bq.x) + acc_r[i][0],
                               s * (acc_i[i][1] + bq.y) + acc_r[i][1],
                               s * (acc_i[i][2] + bq.z) + acc_r[i][2],
                               s * (acc_i[i][3] + bq.w) + acc_r[i][3]);
        if (relu) {
            v.x = fmaxf(v.x, 0.f); v.y = fmaxf(v.y, 0.f);
            v.z = fmaxf(v.z, 0.f); v.w = fmaxf(v.w, 0.f);
        }
        *(float4*)(OUT + ((size_t)r << 7) + (c << 2)) = v;
    }
}

// ---- CSR build (once per launch; edges fixed) ----

__launch_bounds__(256)
__global__ void zero_int(int* __restrict__ p, int n)
{
    const int i = blockIdx.x * 256 + threadIdx.x;
    if (i < n) p[i] = 0;
}

__launch_bounds__(256)
__global__ void hist_kernel(const int* __restrict__ ei, int* __restrict__ counts, int E)
{
    const int e = blockIdx.x * 256 + threadIdx.x;
    if (e < E) atomicAdd(&counts[ei[E + e]], 1);
}

// phase 1: per-block exclusive scan of 256 counts + per-block totals
__launch_bounds__(256)
__global__ void scan_phase1(const int* __restrict__ counts, int* __restrict__ rowstart,
                            int* __restrict__ blocksums, int N)
{
    __shared__ int sdata[256];
    const int t = threadIdx.x;
    const int i = blockIdx.x * 256 + t;
    const int v = (i < N) ? counts[i] : 0;
    sdata[t] = v;
    __syncthreads();
    for (int off = 1; off < 256; off <<= 1) {
        const int add = (t >= off) ? sdata[t - off] : 0;
        __syncthreads();
        sdata[t] += add;
        __syncthreads();
    }
    if (i < N) rowstart[i] = sdata[t] - v;           // intra-block exclusive
    if (t == 255) blocksums[blockIdx.x] = sdata[255];
}

// phase 2: single-block exclusive scan of block sums (nb <= few hundred)
__launch_bounds__(256)
__global__ void scan_phase2(int* __restrict__ bs, int nb)
{
    __shared__ int sdata[256];
    const int t = threadIdx.x;
    int carry = 0;
    for (int base = 0; base < nb; base += 256) {
        const int i = base + t;
        const int v = (i < nb) ? bs[i] : 0;
        sdata[t] = v;
        __syncthreads();
        for (int off = 1; off < 256; off <<= 1) {
            const int add = (t >= off) ? sdata[t - off] : 0;
            __syncthreads();
            sdata[t] += add;
            __syncthreads();
        }
        if (i < nb) bs[i] = carry + sdata[t] - v;
        const int tot = sdata[255];
        __syncthreads();
        carry += tot;
    }
}

// phase 3: add block offsets; emit cursor copy + float degree + rowstart[N]
__launch_bounds__(256)
__global__ void scan_phase3(const int* __restrict__ counts, const int* __restrict__ bs,
                            int* __restrict__ rowstart, int* __restrict__ cursor,
                            float* __restrict__ degf, int N, int E)
{
    const int i = blockIdx.x * 256 + threadIdx.x;
    if (i < N) {
        const int rs = rowstart[i] + bs[blockIdx.x];
        rowstart[i] = rs;
        cursor[i]   = rs;
        degf[i]     = (float)counts[i];
    }
    if (i == 0) rowstart[N] = E;
}

__launch_bounds__(256)
__global__ void build_elist(const int* __restrict__ ei, int* __restrict__ cursor,
                            int2* __restrict__ elist, int E)
{
    const int e = blockIdx.x * 256 + threadIdx.x;
    if (e >= E) return;
    const int d = ei[E + e];
    const int pos = atomicAdd(&cursor[d], 1);
    elist[pos] = make_int2(ei[e], e);   // (src node, edge id)
}

// ---- gather aggregations (atomic-free) ----

// agg[node] = sum over in-edges of h[src]; one wave per dst node, float2/lane.
__launch_bounds__(256)
__global__ void gather_h(const int2* __restrict__ elist, const int* __restrict__ rowstart,
                         const float* __restrict__ h, float* __restrict__ agg, int N)
{
    const int node = blockIdx.x * 4 + (threadIdx.x >> 6);
    if (node >= N) return;
    const int lane = threadIdx.x & 63;
    const int beg = rowstart[node];
    const int end = rowstart[node + 1];
    float2 acc = make_float2(0.f, 0.f);
    int k = beg;
    for (; k + 1 < end; k += 2) {
        const int s0 = elist[k].x;
        const int s1 = elist[k + 1].x;
        const float2 v0 = *(const float2*)&h[((size_t)s0 << 7) + (lane << 1)];
        const float2 v1 = *(const float2*)&h[((size_t)s1 << 7) + (lane << 1)];
        acc.x += v0.x + v1.x;
        acc.y += v0.y + v1.y;
    }
    if (k < end) {
        const int s = elist[k].x;
        const float2 v = *(const float2*)&h[((size_t)s << 7) + (lane << 1)];
        acc.x += v.x; acc.y += v.y;
    }
    *(float2*)&agg[((size_t)node << 7) + (lane << 1)] = acc;
}

// aggef[node] = sum over in-edges of ef[e]; 16 lanes per node.
__launch_bounds__(256)
__global__ void gather_ef(const int2* __restrict__ elist, const int* __restrict__ rowstart,
                          const float* __restrict__ ef, float* __restrict__ aggef, int N)
{
    const int node = blockIdx.x * 16 + (threadIdx.x >> 4);
    if (node >= N) return;
    const int lane = threadIdx.x & 15;
    const int beg = rowstart[node];
    const int end = rowstart[node + 1];
    float acc = 0.f;
    for (int k = beg; k < end; ++k) {
        const int e = elist[k].y;
        acc += ef[((size_t)e << 4) + lane];
    }
    aggef[((size_t)node << 4) + lane] = acc;
}

// pred[q,:2] = concat(x2[a], x2[b]) @ lpW + lpb  — one wave per query
__launch_bounds__(256)
__global__ void head_kernel(const float* __restrict__ x2, const int* __restrict__ eli,
                            const float* __restrict__ lpW, const float* __restrict__ lpb,
                            float* __restrict__ out, int Q)
{
    const long long gt = (long long)blockIdx.x * 256 + threadIdx.x;
    const int q = (int)(gt >> 6);
    if (q >= Q) return;
    const int lane = threadIdx.x & 63;
    const int a = eli[q];
    const int b = eli[Q + q];
    const float* rowp = (lane < 32)
        ? x2 + ((size_t)a << 7) + (lane << 2)
        : x2 + ((size_t)b << 7) + ((lane - 32) << 2);
    const float4 v = *(const float4*)rowp;
    const int k0 = lane << 2;
    const float4 wA = *(const float4*)(lpW + (k0 << 1));
    const float4 wB = *(const float4*)(lpW + (k0 << 1) + 4);
    float c0 = v.x * wA.x + v.y * wA.z + v.z * wB.x + v.w * wB.z;
    float c1 = v.x * wA.y + v.y * wA.w + v.z * wB.y + v.w * wB.w;
#pragma unroll
    for (int off = 32; off > 0; off >>= 1) {
        c0 += __shfl_down(c0, off);
        c1 += __shfl_down(c1, off);
    }
    if (lane == 0) {
        out[(size_t)q * 2 + 0] = c0 + lpb[0];
        out[(size_t)q * 2 + 1] = c1 + lpb[1];
    }
}

extern "C" void kernel_launch(void* const* d_in, const int* in_sizes, int n_in,
                              void* d_out, int out_size, void* d_ws, size_t ws_size,
                              hipStream_t stream)
{
    const float* nf   = (const float*)d_in[0];
    const int*   ei   = (const int*)d_in[1];
    const float* ef   = (const float*)d_in[2];
    const int*   eli  = (const int*)d_in[3];
    const float* c1pW = (const float*)d_in[4];
    const float* c1pb = (const float*)d_in[5];
    const float* c1mW = (const float*)d_in[6];
    const float* c1mb = (const float*)d_in[7];
    const float* c2pW = (const float*)d_in[8];
    const float* c2pb = (const float*)d_in[9];
    const float* c2mW = (const float*)d_in[10];
    const float* c2mb = (const float*)d_in[11];
    const float* lpW  = (const float*)d_in[12];
    const float* lpb  = (const float*)d_in[13];
    float* out = (float*)d_out;

    const int N = in_sizes[0] / 128;
    const int E = in_sizes[1] / 2;
    const int Q = in_sizes[3] / 2;
    const int nb = (N + 255) / 256;

    // workspace layout
    float* A   = (float*)d_ws;                 // N*128  (h)
    float* C   = A + (size_t)N * 128;          // N*128  (x)
    float* B   = C + (size_t)N * 128;          // N*128  (gathered agg)
    float* EFA = B + (size_t)N * 128;          // N*16
    float* DEG = EFA + (size_t)N * 16;         // N (float degree)
    int* counts    = (int*)(DEG + N);          // N
    int* rowstart  = counts + N;               // N+1
    int* cursor    = rowstart + N + 1;         // N
    int* blocksums = cursor + N;               // nb (pad 1024)
    uintptr_t ep = (uintptr_t)(blocksums + 1024);
    ep = (ep + 7) & ~(uintptr_t)7;
    int2* elist = (int2*)ep;                   // E int2 (src, edge id)

    const int gemmGrid = (N + 31) / 32;
    const int eGrid    = (E + 255) / 256;
    const int nGrid    = (N + 255) / 256;
    const int ghGrid   = (N + 3) / 4;
    const int geGrid   = (N + 15) / 16;
    const int headGrid = (int)(((long long)Q * 64 + 255) / 256);

    // ---- CSR build (shared by both convs) ----
    zero_int<<<nGrid, 256, 0, stream>>>(counts, N);
    hist_kernel<<<eGrid, 256, 0, stream>>>(ei, counts, E);
    scan_phase1<<<nGrid, 256, 0, stream>>>(counts, rowstart, blocksums, N);
    scan_phase2<<<1, 256, 0, stream>>>(blocksums, nb);
    scan_phase3<<<nGrid, 256, 0, stream>>>(counts, blocksums, rowstart, cursor, DEG, N, E);
    build_elist<<<eGrid, 256, 0, stream>>>(ei, cursor, elist, E);
    gather_ef<<<geGrid, 256, 0, stream>>>(elist, rowstart, ef, EFA, N);

    // ---- conv1 ----
    gemm_tiled<<<gemmGrid, 256, 0, stream>>>(nf, c1pW, c1pb, A, N);
    gather_h<<<ghGrid, 256, 0, stream>>>(elist, rowstart, A, B, N);
    fused_msg<<<gemmGrid, 256, 0, stream>>>(A, B, EFA, DEG, c1mW, c1mb, C, N, 1);

    // ---- conv2 ----
    gemm_tiled<<<gemmGrid, 256, 0, stream>>>(C, c2pW, c2pb, A, N);
    gather_h<<<ghGrid, 256, 0, stream>>>(elist, rowstart, A, B, N);
    fused_msg<<<gemmGrid, 256, 0, stream>>>(A, B, EFA, DEG, c2mW, c2mb, C, N, 0);

    // ---- head ----
    head_kernel<<<headGrid, 256, 0, stream>>>(C, eli, lpW, lpb, out, Q);
}

// Round 4
// 831.409 us; speedup vs baseline: 7.3585x; 7.3585x over previous
//
#include <hip/hip_runtime.h>
#include <cstdint>
#include <cstddef>

// ---------------------------------------------------------------------------
// Net_25950192402497: 2-layer MLP-message GNN + link-prediction head.
// Identity: segment_sum(concat(x_i,x_j,ef)@W + b) over dst
//   = deg*(h@Wi + b) + (gather-sum h[src])@Wj + (gather-sum ef)@We
// R4: fused message GEMM with SINGLE accumulator — deg*(A@Wi) == (deg*A)@Wi,
// so A is deg-prescaled while staging to LDS and Wi/Wj/We phases share one
// 4x4 acc (R3's dual-acc version hit 256 VGPRs -> 6.6GB spill traffic).
// One reused 16KB xs buffer: LDS 48KB -> 3 blocks/CU.
// ---------------------------------------------------------------------------

// Pre-conv GEMM: OUT[r,0:128] = relu(X[r,0:128] @ W[128,128] + bias)
__launch_bounds__(256)
__global__ void gemm_tiled(const float* __restrict__ X, const float* __restrict__ W,
                           const float* __restrict__ bias, float* __restrict__ OUT,
                           int Nrows)
{
    __shared__ float ws[64 * 128];   // 32 KB: K-tile of W
    __shared__ float xs[32 * 128];   // 16 KB: 32 staged input rows
    const int tid = threadIdx.x;
    const int c  = tid & 31;         // column quad: cols 4c..4c+3
    const int rg = tid >> 5;         // row group: rows 4rg..4rg+3
    const int row0 = blockIdx.x << 5;

    for (int idx = tid; idx < 32 * 128; idx += 256) {
        const int r = idx >> 7;
        const int k = idx & 127;
        const int gr = row0 + r;
        xs[idx] = (gr < Nrows) ? X[((size_t)gr << 7) + k] : 0.0f;
    }

    float acc[4][4];
#pragma unroll
    for (int i = 0; i < 4; ++i)
#pragma unroll
        for (int j = 0; j < 4; ++j) acc[i][j] = 0.0f;

    for (int kt = 0; kt < 128; kt += 64) {
        __syncthreads();
        for (int idx = tid; idx < 64 * 128; idx += 256)
            ws[idx] = W[((size_t)kt << 7) + idx];
        __syncthreads();
        for (int k = 0; k < 64; k += 4) {
            const float4 w0 = *(const float4*)&ws[((k + 0) << 7) + (c << 2)];
            const float4 w1 = *(const float4*)&ws[((k + 1) << 7) + (c << 2)];
            const float4 w2 = *(const float4*)&ws[((k + 2) << 7) + (c << 2)];
            const float4 w3 = *(const float4*)&ws[((k + 3) << 7) + (c << 2)];
#pragma unroll
            for (int i = 0; i < 4; ++i) {
                const int r = (rg << 2) + i;
                const float4 xq = *(const float4*)&xs[(r << 7) + kt + k];
                acc[i][0] += xq.x * w0.x + xq.y * w1.x + xq.z * w2.x + xq.w * w3.x;
                acc[i][1] += xq.x * w0.y + xq.y * w1.y + xq.z * w2.y + xq.w * w3.y;
                acc[i][2] += xq.x * w0.z + xq.y * w1.z + xq.z * w2.z + xq.w * w3.z;
                acc[i][3] += xq.x * w0.w + xq.y * w1.w + xq.z * w2.w + xq.w * w3.w;
            }
        }
    }

#pragma unroll
    for (int i = 0; i < 4; ++i) {
        const int r = row0 + (rg << 2) + i;
        if (r >= Nrows) continue;
        const float4 bq = *(const float4*)&bias[c << 2];
        float4 v = make_float4(fmaxf(acc[i][0] + bq.x, 0.f),
                               fmaxf(acc[i][1] + bq.y, 0.f),
                               fmaxf(acc[i][2] + bq.z, 0.f),
                               fmaxf(acc[i][3] + bq.w, 0.f));
        *(float4*)(OUT + ((size_t)r << 7) + (c << 2)) = v;
    }
}

// Fused message GEMM, single accumulator:
// OUT[r] = act( (deg[r]*A[r])@Wi + B[r]@Wj + EFA[r]@We + deg[r]*b )
// W rows 0..127 = Wi, 128..255 = Wj, 256..271 = We (shape 272x128).
__launch_bounds__(256)
__global__ void fused_msg(const float* __restrict__ A, const float* __restrict__ B,
                          const float* __restrict__ EFA, const float* __restrict__ DEG,
                          const float* __restrict__ W, const float* __restrict__ bias,
                          float* __restrict__ OUT, int Nrows, int relu)
{
    __shared__ float ws[64 * 128];   // 32 KB
    __shared__ float xs[32 * 128];   // 16 KB, reused across the 3 phases
    const int tid = threadIdx.x;
    const int c  = tid & 31;
    const int rg = tid >> 5;
    const int row0 = blockIdx.x << 5;

    float acc[4][4];
#pragma unroll
    for (int i = 0; i < 4; ++i)
#pragma unroll
        for (int j = 0; j < 4; ++j) acc[i][j] = 0.0f;

    // ---- phase 0: X = deg*A, W rows 0..127 ----
    for (int idx = tid; idx < 32 * 128; idx += 256) {
        const int r = idx >> 7;
        const int k = idx & 127;
        const int gr = row0 + r;
        xs[idx] = (gr < Nrows) ? A[((size_t)gr << 7) + k] * DEG[gr] : 0.0f;
    }
    for (int kt = 0; kt < 128; kt += 64) {
        __syncthreads();
        for (int idx = tid; idx < 64 * 128; idx += 256)
            ws[idx] = W[((size_t)kt << 7) + idx];
        __syncthreads();
        for (int k = 0; k < 64; k += 4) {
            const float4 w0 = *(const float4*)&ws[((k + 0) << 7) + (c << 2)];
            const float4 w1 = *(const float4*)&ws[((k + 1) << 7) + (c << 2)];
            const float4 w2 = *(const float4*)&ws[((k + 2) << 7) + (c << 2)];
            const float4 w3 = *(const float4*)&ws[((k + 3) << 7) + (c << 2)];
#pragma unroll
            for (int i = 0; i < 4; ++i) {
                const int r = (rg << 2) + i;
                const float4 xq = *(const float4*)&xs[(r << 7) + kt + k];
                acc[i][0] += xq.x * w0.x + xq.y * w1.x + xq.z * w2.x + xq.w * w3.x;
                acc[i][1] += xq.x * w0.y + xq.y * w1.y + xq.z * w2.y + xq.w * w3.y;
                acc[i][2] += xq.x * w0.z + xq.y * w1.z + xq.z * w2.z + xq.w * w3.z;
                acc[i][3] += xq.x * w0.w + xq.y * w1.w + xq.z * w2.w + xq.w * w3.w;
            }
        }
    }

    // ---- phase 1: X = B, W rows 128..255 ----
    __syncthreads();
    for (int idx = tid; idx < 32 * 128; idx += 256) {
        const int r = idx >> 7;
        const int k = idx & 127;
        const int gr = row0 + r;
        xs[idx] = (gr < Nrows) ? B[((size_t)gr << 7) + k] : 0.0f;
    }
    for (int kt = 0; kt < 128; kt += 64) {
        __syncthreads();
        for (int idx = tid; idx < 64 * 128; idx += 256)
            ws[idx] = W[((size_t)(128 + kt) << 7) + idx];
        __syncthreads();
        for (int k = 0; k < 64; k += 4) {
            const float4 w0 = *(const float4*)&ws[((k + 0) << 7) + (c << 2)];
            const float4 w1 = *(const float4*)&ws[((k + 1) << 7) + (c << 2)];
            const float4 w2 = *(const float4*)&ws[((k + 2) << 7) + (c << 2)];
            const float4 w3 = *(const float4*)&ws[((k + 3) << 7) + (c << 2)];
#pragma unroll
            for (int i = 0; i < 4; ++i) {
                const int r = (rg << 2) + i;
                const float4 xq = *(const float4*)&xs[(r << 7) + kt + k];
                acc[i][0] += xq.x * w0.x + xq.y * w1.x + xq.z * w2.x + xq.w * w3.x;
                acc[i][1] += xq.x * w0.y + xq.y * w1.y + xq.z * w2.y + xq.w * w3.y;
                acc[i][2] += xq.x * w0.z + xq.y * w1.z + xq.z * w2.z + xq.w * w3.z;
                acc[i][3] += xq.x * w0.w + xq.y * w1.w + xq.z * w2.w + xq.w * w3.w;
            }
        }
    }

    // ---- phase 2: X = EFA (K=16), W rows 256..271 ----
    __syncthreads();
    for (int idx = tid; idx < 32 * 16; idx += 256) {
        const int r = idx >> 4;
        const int k = idx & 15;
        const int gr = row0 + r;
        xs[idx] = (gr < Nrows) ? EFA[((size_t)gr << 4) + k] : 0.0f;
    }
    __syncthreads();
    for (int idx = tid; idx < 16 * 128; idx += 256)
        ws[idx] = W[((size_t)256 << 7) + idx];
    __syncthreads();
    for (int k = 0; k < 16; k += 4) {
        const float4 w0 = *(const float4*)&ws[((k + 0) << 7) + (c << 2)];
        const float4 w1 = *(const float4*)&ws[((k + 1) << 7) + (c << 2)];
        const float4 w2 = *(const float4*)&ws[((k + 2) << 7) + (c << 2)];
        const float4 w3 = *(const float4*)&ws[((k + 3) << 7) + (c << 2)];
#pragma unroll
        for (int i = 0; i < 4; ++i) {
            const int r = (rg << 2) + i;
            const float4 xq = *(const float4*)&xs[(r << 4) + k];
            acc[i][0] += xq.x * w0.x + xq.y * w1.x + xq.z * w2.x + xq.w * w3.x;
            acc[i][1] += xq.x * w0.y + xq.y * w1.y + xq.z * w2.y + xq.w * w3.y;
            acc[i][2] += xq.x * w0.z + xq.y * w1.z + xq.z * w2.z + xq.w * w3.z;
            acc[i][3] += xq.x * w0.w + xq.y * w1.w + xq.z * w2.w + xq.w * w3.w;
        }
    }

#pragma unroll
    for (int i = 0; i < 4; ++i) {
        const int r = row0 + (rg << 2) + i;
        if (r >= Nrows) continue;
        const float s = DEG[r];
        const float4 bq = *(const float4*)&bias[c << 2];
        float4 v = make_float4(acc[i][0] + s * bq.x,
                               acc[i][1] + s * bq.y,
                               acc[i][2] + s * bq.z,
                               acc[i][3] + s * bq.w);
        if (relu) {
            v.x = fmaxf(v.x, 0.f); v.y = fmaxf(v.y, 0.f);
            v.z = fmaxf(v.z, 0.f); v.w = fmaxf(v.w, 0.f);
        }
        *(float4*)(OUT + ((size_t)r << 7) + (c << 2)) = v;
    }
}

// ---- CSR build (once per launch; edges fixed) ----

__launch_bounds__(256)
__global__ void zero_int(int* __restrict__ p, int n)
{
    const int i = blockIdx.x * 256 + threadIdx.x;
    if (i < n) p[i] = 0;
}

__launch_bounds__(256)
__global__ void hist_kernel(const int* __restrict__ ei, int* __restrict__ counts, int E)
{
    const int e = blockIdx.x * 256 + threadIdx.x;
    if (e < E) atomicAdd(&counts[ei[E + e]], 1);
}

// phase 1: per-block exclusive scan of 256 counts + per-block totals
__launch_bounds__(256)
__global__ void scan_phase1(const int* __restrict__ counts, int* __restrict__ rowstart,
                            int* __restrict__ blocksums, int N)
{
    __shared__ int sdata[256];
    const int t = threadIdx.x;
    const int i = blockIdx.x * 256 + t;
    const int v = (i < N) ? counts[i] : 0;
    sdata[t] = v;
    __syncthreads();
    for (int off = 1; off < 256; off <<= 1) {
        const int add = (t >= off) ? sdata[t - off] : 0;
        __syncthreads();
        sdata[t] += add;
        __syncthreads();
    }
    if (i < N) rowstart[i] = sdata[t] - v;           // intra-block exclusive
    if (t == 255) blocksums[blockIdx.x] = sdata[255];
}

// phase 2: single-block exclusive scan of block sums
__launch_bounds__(256)
__global__ void scan_phase2(int* __restrict__ bs, int nb)
{
    __shared__ int sdata[256];
    const int t = threadIdx.x;
    int carry = 0;
    for (int base = 0; base < nb; base += 256) {
        const int i = base + t;
        const int v = (i < nb) ? bs[i] : 0;
        sdata[t] = v;
        __syncthreads();
        for (int off = 1; off < 256; off <<= 1) {
            const int add = (t >= off) ? sdata[t - off] : 0;
            __syncthreads();
            sdata[t] += add;
            __syncthreads();
        }
        if (i < nb) bs[i] = carry + sdata[t] - v;
        const int tot = sdata[255];
        __syncthreads();
        carry += tot;
    }
}

// phase 3: add block offsets; emit cursor copy + float degree + rowstart[N]
__launch_bounds__(256)
__global__ void scan_phase3(const int* __restrict__ counts, const int* __restrict__ bs,
                            int* __restrict__ rowstart, int* __restrict__ cursor,
                            float* __restrict__ degf, int N, int E)
{
    const int i = blockIdx.x * 256 + threadIdx.x;
    if (i < N) {
        const int rs = rowstart[i] + bs[blockIdx.x];
        rowstart[i] = rs;
        cursor[i]   = rs;
        degf[i]     = (float)counts[i];
    }
    if (i == 0) rowstart[N] = E;
}

__launch_bounds__(256)
__global__ void build_elist(const int* __restrict__ ei, int* __restrict__ cursor,
                            int2* __restrict__ elist, int E)
{
    const int e = blockIdx.x * 256 + threadIdx.x;
    if (e >= E) return;
    const int d = ei[E + e];
    const int pos = atomicAdd(&cursor[d], 1);
    elist[pos] = make_int2(ei[e], e);   // (src node, edge id)
}

// ---- gather aggregations (atomic-free) ----

// agg[node] = sum over in-edges of h[src]; one wave per dst node, float2/lane.
__launch_bounds__(256)
__global__ void gather_h(const int2* __restrict__ elist, const int* __restrict__ rowstart,
                         const float* __restrict__ h, float* __restrict__ agg, int N)
{
    const int node = blockIdx.x * 4 + (threadIdx.x >> 6);
    if (node >= N) return;
    const int lane = threadIdx.x & 63;
    const int beg = rowstart[node];
    const int end = rowstart[node + 1];
    float2 acc = make_float2(0.f, 0.f);
    int k = beg;
    for (; k + 1 < end; k += 2) {
        const int s0 = elist[k].x;
        const int s1 = elist[k + 1].x;
        const float2 v0 = *(const float2*)&h[((size_t)s0 << 7) + (lane << 1)];
        const float2 v1 = *(const float2*)&h[((size_t)s1 << 7) + (lane << 1)];
        acc.x += v0.x + v1.x;
        acc.y += v0.y + v1.y;
    }
    if (k < end) {
        const int s = elist[k].x;
        const float2 v = *(const float2*)&h[((size_t)s << 7) + (lane << 1)];
        acc.x += v.x; acc.y += v.y;
    }
    *(float2*)&agg[((size_t)node << 7) + (lane << 1)] = acc;
}

// aggef[node] = sum over in-edges of ef[e]; 16 lanes per node.
__launch_bounds__(256)
__global__ void gather_ef(const int2* __restrict__ elist, const int* __restrict__ rowstart,
                          const float* __restrict__ ef, float* __restrict__ aggef, int N)
{
    const int node = blockIdx.x * 16 + (threadIdx.x >> 4);
    if (node >= N) return;
    const int lane = threadIdx.x & 15;
    const int beg = rowstart[node];
    const int end = rowstart[node + 1];
    float acc = 0.f;
    for (int k = beg; k < end; ++k) {
        const int e = elist[k].y;
        acc += ef[((size_t)e << 4) + lane];
    }
    aggef[((size_t)node << 4) + lane] = acc;
}

// pred[q,:2] = concat(x2[a], x2[b]) @ lpW + lpb  — one wave per query
__launch_bounds__(256)
__global__ void head_kernel(const float* __restrict__ x2, const int* __restrict__ eli,
                            const float* __restrict__ lpW, const float* __restrict__ lpb,
                            float* __restrict__ out, int Q)
{
    const long long gt = (long long)blockIdx.x * 256 + threadIdx.x;
    const int q = (int)(gt >> 6);
    if (q >= Q) return;
    const int lane = threadIdx.x & 63;
    const int a = eli[q];
    const int b = eli[Q + q];
    const float* rowp = (lane < 32)
        ? x2 + ((size_t)a << 7) + (lane << 2)
        : x2 + ((size_t)b << 7) + ((lane - 32) << 2);
    const float4 v = *(const float4*)rowp;
    const int k0 = lane << 2;
    const float4 wA = *(const float4*)(lpW + (k0 << 1));
    const float4 wB = *(const float4*)(lpW + (k0 << 1) + 4);
    float c0 = v.x * wA.x + v.y * wA.z + v.z * wB.x + v.w * wB.z;
    float c1 = v.x * wA.y + v.y * wA.w + v.z * wB.y + v.w * wB.w;
#pragma unroll
    for (int off = 32; off > 0; off >>= 1) {
        c0 += __shfl_down(c0, off);
        c1 += __shfl_down(c1, off);
    }
    if (lane == 0) {
        out[(size_t)q * 2 + 0] = c0 + lpb[0];
        out[(size_t)q * 2 + 1] = c1 + lpb[1];
    }
}

extern "C" void kernel_launch(void* const* d_in, const int* in_sizes, int n_in,
                              void* d_out, int out_size, void* d_ws, size_t ws_size,
                              hipStream_t stream)
{
    const float* nf   = (const float*)d_in[0];
    const int*   ei   = (const int*)d_in[1];
    const float* ef   = (const float*)d_in[2];
    const int*   eli  = (const int*)d_in[3];
    const float* c1pW = (const float*)d_in[4];
    const float* c1pb = (const float*)d_in[5];
    const float* c1mW = (const float*)d_in[6];
    const float* c1mb = (const float*)d_in[7];
    const float* c2pW = (const float*)d_in[8];
    const float* c2pb = (const float*)d_in[9];
    const float* c2mW = (const float*)d_in[10];
    const float* c2mb = (const float*)d_in[11];
    const float* lpW  = (const float*)d_in[12];
    const float* lpb  = (const float*)d_in[13];
    float* out = (float*)d_out;

    const int N = in_sizes[0] / 128;
    const int E = in_sizes[1] / 2;
    const int Q = in_sizes[3] / 2;
    const int nb = (N + 255) / 256;

    // workspace layout
    float* A   = (float*)d_ws;                 // N*128  (h)
    float* C   = A + (size_t)N * 128;          // N*128  (x)
    float* B   = C + (size_t)N * 128;          // N*128  (gathered agg)
    float* EFA = B + (size_t)N * 128;          // N*16
    float* DEG = EFA + (size_t)N * 16;         // N (float degree)
    int* counts    = (int*)(DEG + N);          // N
    int* rowstart  = counts + N;               // N+1
    int* cursor    = rowstart + N + 1;         // N
    int* blocksums = cursor + N;               // nb (pad 1024)
    uintptr_t ep = (uintptr_t)(blocksums + 1024);
    ep = (ep + 7) & ~(uintptr_t)7;
    int2* elist = (int2*)ep;                   // E int2 (src, edge id)

    const int gemmGrid = (N + 31) / 32;
    const int eGrid    = (E + 255) / 256;
    const int nGrid    = (N + 255) / 256;
    const int ghGrid   = (N + 3) / 4;
    const int geGrid   = (N + 15) / 16;
    const int headGrid = (int)(((long long)Q * 64 + 255) / 256);

    // ---- CSR build (shared by both convs) ----
    zero_int<<<nGrid, 256, 0, stream>>>(counts, N);
    hist_kernel<<<eGrid, 256, 0, stream>>>(ei, counts, E);
    scan_phase1<<<nGrid, 256, 0, stream>>>(counts, rowstart, blocksums, N);
    scan_phase2<<<1, 256, 0, stream>>>(blocksums, nb);
    scan_phase3<<<nGrid, 256, 0, stream>>>(counts, blocksums, rowstart, cursor, DEG, N, E);
    build_elist<<<eGrid, 256, 0, stream>>>(ei, cursor, elist, E);
    gather_ef<<<geGrid, 256, 0, stream>>>(elist, rowstart, ef, EFA, N);

    // ---- conv1 ----
    gemm_tiled<<<gemmGrid, 256, 0, stream>>>(nf, c1pW, c1pb, A, N);
    gather_h<<<ghGrid, 256, 0, stream>>>(elist, rowstart, A, B, N);
    fused_msg<<<gemmGrid, 256, 0, stream>>>(A, B, EFA, DEG, c1mW, c1mb, C, N, 1);

    // ---- conv2 ----
    gemm_tiled<<<gemmGrid, 256, 0, stream>>>(C, c2pW, c2pb, A, N);
    gather_h<<<ghGrid, 256, 0, stream>>>(elist, rowstart, A, B, N);
    fused_msg<<<gemmGrid, 256, 0, stream>>>(A, B, EFA, DEG, c2mW, c2mb, C, N, 0);

    // ---- head ----
    head_kernel<<<headGrid, 256, 0, stream>>>(C, eli, lpW, lpb, out, Q);
}

// Round 5
// 468.876 us; speedup vs baseline: 13.0480x; 1.7732x over previous
//
#include <hip/hip_runtime.h>
#include <cstdint>
#include <cstddef>

// ---------------------------------------------------------------------------
// Net_25950192402497: 2-layer MLP-message GNN + link-prediction head.
// Identity: segment_sum(concat(x_i,x_j,ef)@W + b) over dst
//   = deg*(h@Wi + b) + (gather-sum h[src])@Wj + (gather-sum ef)@We
// R5: all heavy GEMMs moved to bf16 MFMA (16x16x32, fp32 accumulate).
// fp32-VALU GEMM plateaued at 9.4 TF (6% of peak); threshold 8.36 leaves
// room for bf16 input rounding (~0.4%/layer). Weights pre-transposed to
// Wt[n][k] so B-fragments are contiguous ds_read_b128. Msg K=272 padded
// to 288. bf16 activations also halve gather traffic.
// ---------------------------------------------------------------------------

typedef __attribute__((ext_vector_type(8))) short short8;
typedef __attribute__((ext_vector_type(4))) float float4v;

__device__ __forceinline__ ushort f2b(float f) {
    uint u = __float_as_uint(f);
    u = u + 0x7fff + ((u >> 16) & 1);          // round-to-nearest-even
    return (ushort)(u >> 16);
}
__device__ __forceinline__ float b2f(ushort h) {
    return __uint_as_float(((uint)h) << 16);
}

#define F_MSG     1   // stage X = [deg*A | B | EF | 0] (K=288)
#define F_RELU    2
#define F_DEGBIAS 4   // bias scaled per-row by DEG
#define F_OUTF    8   // write fp32 output
#define F_OUTB    16  // write bf16 output

// MFMA GEMM: OUT[r,0:128] = act( X[r,0:K] @ W[K,128] + bias ), X staged bf16.
// Wt is bf16 TRANSPOSED [n=128][k=K]. Block: 32 rows x 128 cols, 4 waves.
// Wave layout: mi = wave&1 (16-row tile), n0 = (wave>>1)*64 (4 n-tiles of 16).
__launch_bounds__(256)
__global__ void gemm_mfma(const ushort* __restrict__ A, const ushort* __restrict__ B,
                          const ushort* __restrict__ EF, const float* __restrict__ DEG,
                          const ushort* __restrict__ Wt, const float* __restrict__ bias,
                          float* __restrict__ outF, ushort* __restrict__ outB,
                          int M, int K, int flags)
{
    __shared__ ushort xs[32 * 288];   // 18 KB max (K<=288)
    __shared__ ushort ws[128 * 64];   // 16 KB: 64-k chunk of Wt
    const int tid  = threadIdx.x;
    const int lane = tid & 63;
    const int wave = tid >> 6;
    const int row0 = blockIdx.x << 5;
    const int KS   = K;               // xs row stride

    // ---- stage X (bf16) ----
    if (flags & F_MSG) {
        for (int idx = tid; idx < 32 * 64; idx += 256) {   // uints over 128 cols
            const int r  = idx >> 6;
            const int k2 = idx & 63;
            const int gr = row0 + r;
            uint av = 0, bv = 0;
            if (gr < M) {
                const uint a2 = *(const uint*)&A[((size_t)gr << 7) + (k2 << 1)];
                const float d = DEG[gr];
                const ushort lo = f2b(b2f((ushort)(a2 & 0xffff)) * d);
                const ushort hi = f2b(b2f((ushort)(a2 >> 16)) * d);
                av = (uint)lo | ((uint)hi << 16);
                bv = *(const uint*)&B[((size_t)gr << 7) + (k2 << 1)];
            }
            *(uint*)&xs[r * 288 + (k2 << 1)]       = av;
            *(uint*)&xs[r * 288 + 128 + (k2 << 1)] = bv;
        }
        for (int idx = tid; idx < 32 * 16; idx += 256) {   // EF (8 uints) + zero pad (8)
            const int r  = idx >> 4;
            const int k2 = idx & 15;
            const int gr = row0 + r;
            uint v = 0;
            if (k2 < 8 && gr < M) v = *(const uint*)&EF[((size_t)gr << 4) + (k2 << 1)];
            *(uint*)&xs[r * 288 + 256 + (k2 << 1)] = v;
        }
    } else {
        for (int idx = tid; idx < 32 * 64; idx += 256) {   // K=128 plain copy
            const int r  = idx >> 6;
            const int k2 = idx & 63;
            const int gr = row0 + r;
            const uint v = (gr < M) ? *(const uint*)&A[((size_t)gr << 7) + (k2 << 1)] : 0;
            *(uint*)&xs[r * 128 + (k2 << 1)] = v;
        }
    }

    float4v acc[4];
#pragma unroll
    for (int t = 0; t < 4; ++t) acc[t] = (float4v){0.f, 0.f, 0.f, 0.f};

    const int mi   = wave & 1;
    const int n0   = (wave >> 1) << 6;
    const int arow = (mi << 4) + (lane & 15);
    const int aoff = arow * KS + ((lane >> 4) << 3);
    const int bcol = lane & 15;
    const int bqof = (lane >> 4) << 3;

    for (int kt = 0; kt < K; kt += 64) {
        __syncthreads();
        // stage ws[n][0..63] <- Wt[n][kt..kt+64), zero-fill past K
        for (int idx = tid; idx < 128 * 32; idx += 256) {  // uints
            const int n  = idx >> 5;
            const int k2 = idx & 31;
            const int kk = kt + (k2 << 1);
            const uint v = (kk < K) ? *(const uint*)&Wt[(size_t)n * K + kk] : 0;
            *(uint*)&ws[(n << 6) + (k2 << 1)] = v;
        }
        __syncthreads();
#pragma unroll
        for (int s = 0; s < 64; s += 32) {
            if (kt + s >= K) break;
            const short8 af = *(const short8*)&xs[aoff + kt + s];
#pragma unroll
            for (int t = 0; t < 4; ++t) {
                const short8 bf = *(const short8*)&ws[((n0 + (t << 4) + bcol) << 6) + s + bqof];
                acc[t] = __builtin_amdgcn_mfma_f32_16x16x32_bf16(af, bf, acc[t], 0, 0, 0);
            }
        }
    }

    // ---- epilogue: C/D layout col=lane&15, row=(lane>>4)*4+reg ----
    const int rbase = row0 + (mi << 4) + ((lane >> 4) << 2);
    const int cbase = n0 + (lane & 15);
#pragma unroll
    for (int t = 0; t < 4; ++t) {
        const int col = cbase + (t << 4);
        const float bc = bias[col];
#pragma unroll
        for (int r = 0; r < 4; ++r) {
            const int row = rbase + r;
            if (row >= M) continue;
            float v = acc[t][r];
            v += (flags & F_DEGBIAS) ? DEG[row] * bc : bc;
            if (flags & F_RELU) v = fmaxf(v, 0.f);
            if (flags & F_OUTF) outF[((size_t)row << 7) + col] = v;
            if (flags & F_OUTB) outB[((size_t)row << 7) + col] = f2b(v);
        }
    }
}

// ---- CSR build (once per launch; edges fixed) ----

__launch_bounds__(256)
__global__ void zero_int(int* __restrict__ p, int n)
{
    const int i = blockIdx.x * 256 + threadIdx.x;
    if (i < n) p[i] = 0;
}

__launch_bounds__(256)
__global__ void hist_kernel(const int* __restrict__ ei, int* __restrict__ counts, int E)
{
    const int e = blockIdx.x * 256 + threadIdx.x;
    if (e < E) atomicAdd(&counts[ei[E + e]], 1);
}

__launch_bounds__(256)
__global__ void scan_phase1(const int* __restrict__ counts, int* __restrict__ rowstart,
                            int* __restrict__ blocksums, int N)
{
    __shared__ int sdata[256];
    const int t = threadIdx.x;
    const int i = blockIdx.x * 256 + t;
    const int v = (i < N) ? counts[i] : 0;
    sdata[t] = v;
    __syncthreads();
    for (int off = 1; off < 256; off <<= 1) {
        const int add = (t >= off) ? sdata[t - off] : 0;
        __syncthreads();
        sdata[t] += add;
        __syncthreads();
    }
    if (i < N) rowstart[i] = sdata[t] - v;
    if (t == 255) blocksums[blockIdx.x] = sdata[255];
}

__launch_bounds__(256)
__global__ void scan_phase2(int* __restrict__ bs, int nb)
{
    __shared__ int sdata[256];
    const int t = threadIdx.x;
    int carry = 0;
    for (int base = 0; base < nb; base += 256) {
        const int i = base + t;
        const int v = (i < nb) ? bs[i] : 0;
        sdata[t] = v;
        __syncthreads();
        for (int off = 1; off < 256; off <<= 1) {
            const int add = (t >= off) ? sdata[t - off] : 0;
            __syncthreads();
            sdata[t] += add;
            __syncthreads();
        }
        if (i < nb) bs[i] = carry + sdata[t] - v;
        const int tot = sdata[255];
        __syncthreads();
        carry += tot;
    }
}

__launch_bounds__(256)
__global__ void scan_phase3(const int* __restrict__ counts, const int* __restrict__ bs,
                            int* __restrict__ rowstart, int* __restrict__ cursor,
                            float* __restrict__ degf, int N, int E)
{
    const int i = blockIdx.x * 256 + threadIdx.x;
    if (i < N) {
        const int rs = rowstart[i] + bs[blockIdx.x];
        rowstart[i] = rs;
        cursor[i]   = rs;
        degf[i]     = (float)counts[i];
    }
    if (i == 0) rowstart[N] = E;
}

__launch_bounds__(256)
__global__ void build_elist(const int* __restrict__ ei, int* __restrict__ cursor,
                            int2* __restrict__ elist, int E)
{
    const int e = blockIdx.x * 256 + threadIdx.x;
    if (e >= E) return;
    const int d = ei[E + e];
    const int pos = atomicAdd(&cursor[d], 1);
    elist[pos] = make_int2(ei[e], e);
}

// ---- gathers (atomic-free) ----

// agg[node] = sum h[src] over in-edges; bf16 in, fp32 accumulate, bf16 out.
__launch_bounds__(256)
__global__ void gather_h_bf(const int2* __restrict__ elist, const int* __restrict__ rowstart,
                            const ushort* __restrict__ h, ushort* __restrict__ agg, int N)
{
    const int node = blockIdx.x * 4 + (threadIdx.x >> 6);
    if (node >= N) return;
    const int lane = threadIdx.x & 63;
    const int beg = rowstart[node];
    const int end = rowstart[node + 1];
    float ax = 0.f, ay = 0.f;
    int k = beg;
    for (; k + 1 < end; k += 2) {
        const int s0 = elist[k].x;
        const int s1 = elist[k + 1].x;
        const uint v0 = *(const uint*)&h[((size_t)s0 << 7) + (lane << 1)];
        const uint v1 = *(const uint*)&h[((size_t)s1 << 7) + (lane << 1)];
        ax += b2f((ushort)(v0 & 0xffff)) + b2f((ushort)(v1 & 0xffff));
        ay += b2f((ushort)(v0 >> 16))    + b2f((ushort)(v1 >> 16));
    }
    if (k < end) {
        const uint v = *(const uint*)&h[((size_t)elist[k].x << 7) + (lane << 1)];
        ax += b2f((ushort)(v & 0xffff));
        ay += b2f((ushort)(v >> 16));
    }
    const uint o = (uint)f2b(ax) | ((uint)f2b(ay) << 16);
    *(uint*)&agg[((size_t)node << 7) + (lane << 1)] = o;
}

// aggef[node] = sum ef[e] (fp32 in), bf16 out; 16 lanes/node.
__launch_bounds__(256)
__global__ void gather_ef(const int2* __restrict__ elist, const int* __restrict__ rowstart,
                          const float* __restrict__ ef, ushort* __restrict__ aggef, int N)
{
    const int node = blockIdx.x * 16 + (threadIdx.x >> 4);
    if (node >= N) return;
    const int lane = threadIdx.x & 15;
    const int beg = rowstart[node];
    const int end = rowstart[node + 1];
    float acc = 0.f;
    for (int k = beg; k < end; ++k)
        acc += ef[((size_t)elist[k].y << 4) + lane];
    aggef[((size_t)node << 4) + lane] = f2b(acc);
}

// ---- converts ----

__launch_bounds__(256)
__global__ void cvt_bf(const float* __restrict__ in, ushort* __restrict__ outp, long long n4)
{
    const long long i = (long long)blockIdx.x * 256 + threadIdx.x;
    if (i >= n4) return;
    const float4 v = *(const float4*)&in[i * 4];
    const uint lo = (uint)f2b(v.x) | ((uint)f2b(v.y) << 16);
    const uint hi = (uint)f2b(v.z) | ((uint)f2b(v.w) << 16);
    *(uint2*)&outp[i * 4] = make_uint2(lo, hi);
}

// Wt[n][k] = bf16(W[k][n]); zero-pad k in [K, Kp).
__launch_bounds__(256)
__global__ void cvt_wt(const float* __restrict__ W, ushort* __restrict__ Wt, int K, int Kp)
{
    const int idx = blockIdx.x * 256 + threadIdx.x;
    if (idx >= 128 * Kp) return;
    const int n = idx / Kp;
    const int k = idx - n * Kp;
    Wt[idx] = (k < K) ? f2b(W[(size_t)k * 128 + n]) : (ushort)0;
}

// pred[q,:2] = concat(x2[a], x2[b]) @ lpW + lpb  — one wave per query (fp32)
__launch_bounds__(256)
__global__ void head_kernel(const float* __restrict__ x2, const int* __restrict__ eli,
                            const float* __restrict__ lpW, const float* __restrict__ lpb,
                            float* __restrict__ out, int Q)
{
    const long long gt = (long long)blockIdx.x * 256 + threadIdx.x;
    const int q = (int)(gt >> 6);
    if (q >= Q) return;
    const int lane = threadIdx.x & 63;
    const int a = eli[q];
    const int b = eli[Q + q];
    const float* rowp = (lane < 32)
        ? x2 + ((size_t)a << 7) + (lane << 2)
        : x2 + ((size_t)b << 7) + ((lane - 32) << 2);
    const float4 v = *(const float4*)rowp;
    const int k0 = lane << 2;
    const float4 wA = *(const float4*)(lpW + (k0 << 1));
    const float4 wB = *(const float4*)(lpW + (k0 << 1) + 4);
    float c0 = v.x * wA.x + v.y * wA.z + v.z * wB.x + v.w * wB.z;
    float c1 = v.x * wA.y + v.y * wA.w + v.z * wB.y + v.w * wB.w;
#pragma unroll
    for (int off = 32; off > 0; off >>= 1) {
        c0 += __shfl_down(c0, off);
        c1 += __shfl_down(c1, off);
    }
    if (lane == 0) {
        out[(size_t)q * 2 + 0] = c0 + lpb[0];
        out[(size_t)q * 2 + 1] = c1 + lpb[1];
    }
}

extern "C" void kernel_launch(void* const* d_in, const int* in_sizes, int n_in,
                              void* d_out, int out_size, void* d_ws, size_t ws_size,
                              hipStream_t stream)
{
    const float* nf   = (const float*)d_in[0];
    const int*   ei   = (const int*)d_in[1];
    const float* ef   = (const float*)d_in[2];
    const int*   eli  = (const int*)d_in[3];
    const float* c1pW = (const float*)d_in[4];
    const float* c1pb = (const float*)d_in[5];
    const float* c1mW = (const float*)d_in[6];
    const float* c1mb = (const float*)d_in[7];
    const float* c2pW = (const float*)d_in[8];
    const float* c2pb = (const float*)d_in[9];
    const float* c2mW = (const float*)d_in[10];
    const float* c2mb = (const float*)d_in[11];
    const float* lpW  = (const float*)d_in[12];
    const float* lpb  = (const float*)d_in[13];
    float* out = (float*)d_out;

    const int N = in_sizes[0] / 128;
    const int E = in_sizes[1] / 2;
    const int Q = in_sizes[3] / 2;
    const int nb = (N + 255) / 256;

    // ---- workspace layout ----
    float* x2f = (float*)d_ws;                 // N*128 fp32 (head input)
    float* DEG = x2f + (size_t)N * 128;        // N
    int* counts    = (int*)(DEG + N);          // N
    int* rowstart  = counts + N;               // N+1
    int* cursor    = rowstart + N + 1;         // N
    int* blocksums = cursor + N;               // 1024 pad
    uintptr_t up = (uintptr_t)(blocksums + 1024);
    up = (up + 15) & ~(uintptr_t)15;
    ushort* nf_bf  = (ushort*)up;              // N*128
    ushort* h_bf   = nf_bf  + (size_t)N * 128; // N*128
    ushort* agg_bf = h_bf   + (size_t)N * 128; // N*128
    ushort* x1_bf  = agg_bf + (size_t)N * 128; // N*128
    ushort* ef_bf  = x1_bf  + (size_t)N * 128; // N*16
    ushort* wtp1   = ef_bf  + (size_t)N * 16;  // 128*128
    ushort* wtm1   = wtp1 + 128 * 128;         // 128*288
    ushort* wtp2   = wtm1 + 128 * 288;         // 128*128
    ushort* wtm2   = wtp2 + 128 * 128;         // 128*288
    uintptr_t ep = (uintptr_t)(wtm2 + 128 * 288);
    ep = (ep + 7) & ~(uintptr_t)7;
    int2* elist = (int2*)ep;                   // E int2 (src, edge id)
    // total ~ 84 MB for N=50k, E=500k

    const int gemmGrid = (N + 31) / 32;
    const int eGrid    = (E + 255) / 256;
    const int nGrid    = (N + 255) / 256;
    const int ghGrid   = (N + 3) / 4;
    const int geGrid   = (N + 15) / 16;
    const int headGrid = (int)(((long long)Q * 64 + 255) / 256);

    // ---- CSR build ----
    zero_int<<<nGrid, 256, 0, stream>>>(counts, N);
    hist_kernel<<<eGrid, 256, 0, stream>>>(ei, counts, E);
    scan_phase1<<<nGrid, 256, 0, stream>>>(counts, rowstart, blocksums, N);
    scan_phase2<<<1, 256, 0, stream>>>(blocksums, nb);
    scan_phase3<<<nGrid, 256, 0, stream>>>(counts, blocksums, rowstart, cursor, DEG, N, E);
    build_elist<<<eGrid, 256, 0, stream>>>(ei, cursor, elist, E);
    gather_ef<<<geGrid, 256, 0, stream>>>(elist, rowstart, ef, ef_bf, N);

    // ---- converts ----
    cvt_bf<<<(int)(((long long)N * 32 + 255) / 256), 256, 0, stream>>>(nf, nf_bf, (long long)N * 32);
    cvt_wt<<<(128 * 128 + 255) / 256, 256, 0, stream>>>(c1pW, wtp1, 128, 128);
    cvt_wt<<<(128 * 288 + 255) / 256, 256, 0, stream>>>(c1mW, wtm1, 272, 288);
    cvt_wt<<<(128 * 128 + 255) / 256, 256, 0, stream>>>(c2pW, wtp2, 128, 128);
    cvt_wt<<<(128 * 288 + 255) / 256, 256, 0, stream>>>(c2mW, wtm2, 272, 288);

    // ---- conv1 ----
    gemm_mfma<<<gemmGrid, 256, 0, stream>>>(nf_bf, nullptr, nullptr, DEG, wtp1, c1pb,
                                            nullptr, h_bf, N, 128, F_RELU | F_OUTB);
    gather_h_bf<<<ghGrid, 256, 0, stream>>>(elist, rowstart, h_bf, agg_bf, N);
    gemm_mfma<<<gemmGrid, 256, 0, stream>>>(h_bf, agg_bf, ef_bf, DEG, wtm1, c1mb,
                                            nullptr, x1_bf, N, 288,
                                            F_MSG | F_RELU | F_DEGBIAS | F_OUTB);

    // ---- conv2 ----
    gemm_mfma<<<gemmGrid, 256, 0, stream>>>(x1_bf, nullptr, nullptr, DEG, wtp2, c2pb,
                                            nullptr, h_bf, N, 128, F_RELU | F_OUTB);
    gather_h_bf<<<ghGrid, 256, 0, stream>>>(elist, rowstart, h_bf, agg_bf, N);
    gemm_mfma<<<gemmGrid, 256, 0, stream>>>(h_bf, agg_bf, ef_bf, DEG, wtm2, c2mb,
                                            x2f, nullptr, N, 288,
                                            F_MSG | F_DEGBIAS | F_OUTF);

    // ---- head ----
    head_kernel<<<headGrid, 256, 0, stream>>>(x2f, eli, lpW, lpb, out, Q);
}

// Round 6
// 387.913 us; speedup vs baseline: 15.7713x; 1.2087x over previous
//
#include <hip/hip_runtime.h>
#include <cstdint>
#include <cstddef>

// ---------------------------------------------------------------------------
// Net_25950192402497: 2-layer MLP-message GNN + link-prediction head.
// Identity: segment_sum(concat(x_i,x_j,ef)@W + b) over dst
//   = deg*(h@Wi + b) + (gather-sum h[src])@Wj + (gather-sum ef)@We
// R6: MFMA GEMM restructured. R5 had 2.9M LDS bank-conflict cycles: stride
// 64/128-ushort rows put every fragment quad in the same 4 banks (16-way).
// Fix: stride 72 ushorts (144B -> bank 36r+o/2, r/r+8 = 2-way = free).
// Also 64-row x 128-col tiles (weight restaged half as often), K chunked
// by 64, msg-K zero-padded to 320 so every chunk is uniform.
// ---------------------------------------------------------------------------

typedef __attribute__((ext_vector_type(8))) short short8;
typedef __attribute__((ext_vector_type(4))) float float4v;

__device__ __forceinline__ ushort f2b(float f) {
    uint u = __float_as_uint(f);
    u = u + 0x7fff + ((u >> 16) & 1);          // round-to-nearest-even
    return (ushort)(u >> 16);
}
__device__ __forceinline__ float b2f(ushort h) {
    return __uint_as_float(((uint)h) << 16);
}

#define F_MSG     1   // X = [deg*A | B | EF | 0] in k-space (Kp=320)
#define F_RELU    2
#define F_DEGBIAS 4   // bias scaled per-row by DEG
#define F_OUTF    8   // write fp32 output
#define F_OUTB    16  // write bf16 output

#define XS_STRIDE 72  // 144 B: bank-conflict-free (2-way max), 16B-aligned

// MFMA GEMM: OUT[r,0:128] = act( X[r,0:Kp] @ W[Kp,128] + bias ).
// Wt bf16 transposed [n=128][Kp], zero-padded. Kp % 64 == 0.
// Block: 64 rows x 128 cols, 4 waves; wave w owns rows w*16..w*16+15,
// all 128 cols as 8 col-tiles of 16. acc = 8 x float4.
__launch_bounds__(256)
__global__ void gemm_mfma(const ushort* __restrict__ A, const ushort* __restrict__ B,
                          const ushort* __restrict__ EF, const float* __restrict__ DEG,
                          const ushort* __restrict__ Wt, const float* __restrict__ bias,
                          float* __restrict__ outF, ushort* __restrict__ outB,
                          int M, int Kp, int flags)
{
    __shared__ ushort xs[64 * XS_STRIDE];    // 9 KB
    __shared__ ushort ws[128 * XS_STRIDE];   // 18 KB
    const int tid  = threadIdx.x;
    const int lane = tid & 63;
    const int wave = tid >> 6;
    const int row0 = blockIdx.x << 6;

    float4v acc[8];
#pragma unroll
    for (int t = 0; t < 8; ++t) acc[t] = (float4v){0.f, 0.f, 0.f, 0.f};

    const int arow = (wave << 4) + (lane & 15);
    const int koff = (lane >> 4) << 3;       // 0,8,16,24
    const int bcol = lane & 15;

    for (int kt = 0; kt < Kp; kt += 64) {
        __syncthreads();
        // ---- stage ws[n][0..63] <- Wt[n][kt..kt+64) ----
        for (int idx = tid; idx < 128 * 8; idx += 256) {
            const int n = idx >> 3;
            const int g = idx & 7;
            const uint4 v = *(const uint4*)&Wt[(size_t)n * Kp + kt + (g << 3)];
            *(uint4*)&ws[n * XS_STRIDE + (g << 3)] = v;
        }
        // ---- stage xs[r][0..63] ----
        if (flags & F_MSG) {
            for (int idx = tid; idx < 64 * 8; idx += 256) {
                const int r  = idx >> 3;
                const int g  = idx & 7;
                const int gr = row0 + r;
                const int kk = kt + (g << 3);
                uint4 v = make_uint4(0, 0, 0, 0);
                if (gr < M) {
                    if (kk < 128) {                       // deg * A
                        uint4 a = *(const uint4*)&A[((size_t)gr << 7) + kk];
                        const float d = DEG[gr];
                        uint* p = (uint*)&a;
#pragma unroll
                        for (int q = 0; q < 4; ++q) {
                            const ushort lo = f2b(b2f((ushort)(p[q] & 0xffff)) * d);
                            const ushort hi = f2b(b2f((ushort)(p[q] >> 16)) * d);
                            p[q] = (uint)lo | ((uint)hi << 16);
                        }
                        v = a;
                    } else if (kk < 256) {                // B
                        v = *(const uint4*)&B[((size_t)gr << 7) + kk - 128];
                    } else if (kk < 272) {                // EF (16 wide)
                        v = *(const uint4*)&EF[((size_t)gr << 4) + kk - 256];
                    }                                     // else zero pad
                }
                *(uint4*)&xs[r * XS_STRIDE + (g << 3)] = v;
            }
        } else {
            for (int idx = tid; idx < 64 * 8; idx += 256) {
                const int r  = idx >> 3;
                const int g  = idx & 7;
                const int gr = row0 + r;
                uint4 v = make_uint4(0, 0, 0, 0);
                if (gr < M) v = *(const uint4*)&A[((size_t)gr << 7) + kt + (g << 3)];
                *(uint4*)&xs[r * XS_STRIDE + (g << 3)] = v;
            }
        }
        __syncthreads();
        // ---- MFMA: 2 k-steps of 32 ----
#pragma unroll
        for (int s = 0; s < 64; s += 32) {
            const short8 af = *(const short8*)&xs[arow * XS_STRIDE + s + koff];
#pragma unroll
            for (int t = 0; t < 8; ++t) {
                const short8 bf = *(const short8*)&ws[((t << 4) + bcol) * XS_STRIDE + s + koff];
                acc[t] = __builtin_amdgcn_mfma_f32_16x16x32_bf16(af, bf, acc[t], 0, 0, 0);
            }
        }
    }

    // ---- epilogue: C/D layout col=lane&15, row=(lane>>4)*4+reg ----
    const int rbase = row0 + (wave << 4) + ((lane >> 4) << 2);
#pragma unroll
    for (int t = 0; t < 8; ++t) {
        const int col = (t << 4) + bcol;
        const float bc = bias[col];
#pragma unroll
        for (int r = 0; r < 4; ++r) {
            const int row = rbase + r;
            if (row >= M) continue;
            float v = acc[t][r];
            v += (flags & F_DEGBIAS) ? DEG[row] * bc : bc;
            if (flags & F_RELU) v = fmaxf(v, 0.f);
            if (flags & F_OUTF) outF[((size_t)row << 7) + col] = v;
            if (flags & F_OUTB) outB[((size_t)row << 7) + col] = f2b(v);
        }
    }
}

// ---- CSR build (once per launch; edges fixed) ----

__launch_bounds__(256)
__global__ void zero_int(int* __restrict__ p, int n)
{
    const int i = blockIdx.x * 256 + threadIdx.x;
    if (i < n) p[i] = 0;
}

__launch_bounds__(256)
__global__ void hist_kernel(const int* __restrict__ ei, int* __restrict__ counts, int E)
{
    const int e = blockIdx.x * 256 + threadIdx.x;
    if (e < E) atomicAdd(&counts[ei[E + e]], 1);
}

__launch_bounds__(256)
__global__ void scan_phase1(const int* __restrict__ counts, int* __restrict__ rowstart,
                            int* __restrict__ blocksums, int N)
{
    __shared__ int sdata[256];
    const int t = threadIdx.x;
    const int i = blockIdx.x * 256 + t;
    const int v = (i < N) ? counts[i] : 0;
    sdata[t] = v;
    __syncthreads();
    for (int off = 1; off < 256; off <<= 1) {
        const int add = (t >= off) ? sdata[t - off] : 0;
        __syncthreads();
        sdata[t] += add;
        __syncthreads();
    }
    if (i < N) rowstart[i] = sdata[t] - v;
    if (t == 255) blocksums[blockIdx.x] = sdata[255];
}

__launch_bounds__(256)
__global__ void scan_phase2(int* __restrict__ bs, int nb)
{
    __shared__ int sdata[256];
    const int t = threadIdx.x;
    int carry = 0;
    for (int base = 0; base < nb; base += 256) {
        const int i = base + t;
        const int v = (i < nb) ? bs[i] : 0;
        sdata[t] = v;
        __syncthreads();
        for (int off = 1; off < 256; off <<= 1) {
            const int add = (t >= off) ? sdata[t - off] : 0;
            __syncthreads();
            sdata[t] += add;
            __syncthreads();
        }
        if (i < nb) bs[i] = carry + sdata[t] - v;
        const int tot = sdata[255];
        __syncthreads();
        carry += tot;
    }
}

__launch_bounds__(256)
__global__ void scan_phase3(const int* __restrict__ counts, const int* __restrict__ bs,
                            int* __restrict__ rowstart, int* __restrict__ cursor,
                            float* __restrict__ degf, int N, int E)
{
    const int i = blockIdx.x * 256 + threadIdx.x;
    if (i < N) {
        const int rs = rowstart[i] + bs[blockIdx.x];
        rowstart[i] = rs;
        cursor[i]   = rs;
        degf[i]     = (float)counts[i];
    }
    if (i == 0) rowstart[N] = E;
}

__launch_bounds__(256)
__global__ void build_elist(const int* __restrict__ ei, int* __restrict__ cursor,
                            int2* __restrict__ elist, int E)
{
    const int e = blockIdx.x * 256 + threadIdx.x;
    if (e >= E) return;
    const int d = ei[E + e];
    const int pos = atomicAdd(&cursor[d], 1);
    elist[pos] = make_int2(ei[e], e);
}

// ---- gathers (atomic-free) ----

__launch_bounds__(256)
__global__ void gather_h_bf(const int2* __restrict__ elist, const int* __restrict__ rowstart,
                            const ushort* __restrict__ h, ushort* __restrict__ agg, int N)
{
    const int node = blockIdx.x * 4 + (threadIdx.x >> 6);
    if (node >= N) return;
    const int lane = threadIdx.x & 63;
    const int beg = rowstart[node];
    const int end = rowstart[node + 1];
    float ax = 0.f, ay = 0.f;
    int k = beg;
    for (; k + 1 < end; k += 2) {
        const int s0 = elist[k].x;
        const int s1 = elist[k + 1].x;
        const uint v0 = *(const uint*)&h[((size_t)s0 << 7) + (lane << 1)];
        const uint v1 = *(const uint*)&h[((size_t)s1 << 7) + (lane << 1)];
        ax += b2f((ushort)(v0 & 0xffff)) + b2f((ushort)(v1 & 0xffff));
        ay += b2f((ushort)(v0 >> 16))    + b2f((ushort)(v1 >> 16));
    }
    if (k < end) {
        const uint v = *(const uint*)&h[((size_t)elist[k].x << 7) + (lane << 1)];
        ax += b2f((ushort)(v & 0xffff));
        ay += b2f((ushort)(v >> 16));
    }
    const uint o = (uint)f2b(ax) | ((uint)f2b(ay) << 16);
    *(uint*)&agg[((size_t)node << 7) + (lane << 1)] = o;
}

__launch_bounds__(256)
__global__ void gather_ef(const int2* __restrict__ elist, const int* __restrict__ rowstart,
                          const float* __restrict__ ef, ushort* __restrict__ aggef, int N)
{
    const int node = blockIdx.x * 16 + (threadIdx.x >> 4);
    if (node >= N) return;
    const int lane = threadIdx.x & 15;
    const int beg = rowstart[node];
    const int end = rowstart[node + 1];
    float acc = 0.f;
    for (int k = beg; k < end; ++k)
        acc += ef[((size_t)elist[k].y << 4) + lane];
    aggef[((size_t)node << 4) + lane] = f2b(acc);
}

// ---- converts ----

__launch_bounds__(256)
__global__ void cvt_bf(const float* __restrict__ in, ushort* __restrict__ outp, long long n4)
{
    const long long i = (long long)blockIdx.x * 256 + threadIdx.x;
    if (i >= n4) return;
    const float4 v = *(const float4*)&in[i * 4];
    const uint lo = (uint)f2b(v.x) | ((uint)f2b(v.y) << 16);
    const uint hi = (uint)f2b(v.z) | ((uint)f2b(v.w) << 16);
    *(uint2*)&outp[i * 4] = make_uint2(lo, hi);
}

// Wt[n][k] = bf16(W[k][n]); zero-pad k in [K, Kp).
__launch_bounds__(256)
__global__ void cvt_wt(const float* __restrict__ W, ushort* __restrict__ Wt, int K, int Kp)
{
    const int idx = blockIdx.x * 256 + threadIdx.x;
    if (idx >= 128 * Kp) return;
    const int n = idx / Kp;
    const int k = idx - n * Kp;
    Wt[idx] = (k < K) ? f2b(W[(size_t)k * 128 + n]) : (ushort)0;
}

// pred[q,:2] = concat(x2[a], x2[b]) @ lpW + lpb  — one wave per query (fp32)
__launch_bounds__(256)
__global__ void head_kernel(const float* __restrict__ x2, const int* __restrict__ eli,
                            const float* __restrict__ lpW, const float* __restrict__ lpb,
                            float* __restrict__ out, int Q)
{
    const long long gt = (long long)blockIdx.x * 256 + threadIdx.x;
    const int q = (int)(gt >> 6);
    if (q >= Q) return;
    const int lane = threadIdx.x & 63;
    const int a = eli[q];
    const int b = eli[Q + q];
    const float* rowp = (lane < 32)
        ? x2 + ((size_t)a << 7) + (lane << 2)
        : x2 + ((size_t)b << 7) + ((lane - 32) << 2);
    const float4 v = *(const float4*)rowp;
    const int k0 = lane << 2;
    const float4 wA = *(const float4*)(lpW + (k0 << 1));
    const float4 wB = *(const float4*)(lpW + (k0 << 1) + 4);
    float c0 = v.x * wA.x + v.y * wA.z + v.z * wB.x + v.w * wB.z;
    float c1 = v.x * wA.y + v.y * wA.w + v.z * wB.y + v.w * wB.w;
#pragma unroll
    for (int off = 32; off > 0; off >>= 1) {
        c0 += __shfl_down(c0, off);
        c1 += __shfl_down(c1, off);
    }
    if (lane == 0) {
        out[(size_t)q * 2 + 0] = c0 + lpb[0];
        out[(size_t)q * 2 + 1] = c1 + lpb[1];
    }
}

extern "C" void kernel_launch(void* const* d_in, const int* in_sizes, int n_in,
                              void* d_out, int out_size, void* d_ws, size_t ws_size,
                              hipStream_t stream)
{
    const float* nf   = (const float*)d_in[0];
    const int*   ei   = (const int*)d_in[1];
    const float* ef   = (const float*)d_in[2];
    const int*   eli  = (const int*)d_in[3];
    const float* c1pW = (const float*)d_in[4];
    const float* c1pb = (const float*)d_in[5];
    const float* c1mW = (const float*)d_in[6];
    const float* c1mb = (const float*)d_in[7];
    const float* c2pW = (const float*)d_in[8];
    const float* c2pb = (const float*)d_in[9];
    const float* c2mW = (const float*)d_in[10];
    const float* c2mb = (const float*)d_in[11];
    const float* lpW  = (const float*)d_in[12];
    const float* lpb  = (const float*)d_in[13];
    float* out = (float*)d_out;

    const int N = in_sizes[0] / 128;
    const int E = in_sizes[1] / 2;
    const int Q = in_sizes[3] / 2;
    const int nb = (N + 255) / 256;
    const int KP_MSG = 320;   // 272 padded to 5x64

    // ---- workspace layout ----
    float* x2f = (float*)d_ws;                 // N*128 fp32 (head input)
    float* DEG = x2f + (size_t)N * 128;        // N
    int* counts    = (int*)(DEG + N);          // N
    int* rowstart  = counts + N;               // N+1
    int* cursor    = rowstart + N + 1;         // N
    int* blocksums = cursor + N;               // 1024 pad
    uintptr_t up = (uintptr_t)(blocksums + 1024);
    up = (up + 15) & ~(uintptr_t)15;
    ushort* nf_bf  = (ushort*)up;              // N*128
    ushort* h_bf   = nf_bf  + (size_t)N * 128; // N*128
    ushort* agg_bf = h_bf   + (size_t)N * 128; // N*128
    ushort* x1_bf  = agg_bf + (size_t)N * 128; // N*128
    ushort* ef_bf  = x1_bf  + (size_t)N * 128; // N*16
    ushort* wtp1   = ef_bf  + (size_t)N * 16;  // 128*128
    ushort* wtm1   = wtp1 + 128 * 128;         // 128*320
    ushort* wtp2   = wtm1 + 128 * KP_MSG;      // 128*128
    ushort* wtm2   = wtp2 + 128 * 128;         // 128*320
    uintptr_t ep = (uintptr_t)(wtm2 + 128 * KP_MSG);
    ep = (ep + 7) & ~(uintptr_t)7;
    int2* elist = (int2*)ep;                   // E int2 (src, edge id)

    const int gemmGrid = (N + 63) / 64;
    const int eGrid    = (E + 255) / 256;
    const int nGrid    = (N + 255) / 256;
    const int ghGrid   = (N + 3) / 4;
    const int geGrid   = (N + 15) / 16;
    const int headGrid = (int)(((long long)Q * 64 + 255) / 256);

    // ---- CSR build ----
    zero_int<<<nGrid, 256, 0, stream>>>(counts, N);
    hist_kernel<<<eGrid, 256, 0, stream>>>(ei, counts, E);
    scan_phase1<<<nGrid, 256, 0, stream>>>(counts, rowstart, blocksums, N);
    scan_phase2<<<1, 256, 0, stream>>>(blocksums, nb);
    scan_phase3<<<nGrid, 256, 0, stream>>>(counts, blocksums, rowstart, cursor, DEG, N, E);
    build_elist<<<eGrid, 256, 0, stream>>>(ei, cursor, elist, E);
    gather_ef<<<geGrid, 256, 0, stream>>>(elist, rowstart, ef, ef_bf, N);

    // ---- converts ----
    cvt_bf<<<(int)(((long long)N * 32 + 255) / 256), 256, 0, stream>>>(nf, nf_bf, (long long)N * 32);
    cvt_wt<<<(128 * 128 + 255) / 256, 256, 0, stream>>>(c1pW, wtp1, 128, 128);
    cvt_wt<<<(128 * KP_MSG + 255) / 256, 256, 0, stream>>>(c1mW, wtm1, 272, KP_MSG);
    cvt_wt<<<(128 * 128 + 255) / 256, 256, 0, stream>>>(c2pW, wtp2, 128, 128);
    cvt_wt<<<(128 * KP_MSG + 255) / 256, 256, 0, stream>>>(c2mW, wtm2, 272, KP_MSG);

    // ---- conv1 ----
    gemm_mfma<<<gemmGrid, 256, 0, stream>>>(nf_bf, nullptr, nullptr, DEG, wtp1, c1pb,
                                            nullptr, h_bf, N, 128, F_RELU | F_OUTB);
    gather_h_bf<<<ghGrid, 256, 0, stream>>>(elist, rowstart, h_bf, agg_bf, N);
    gemm_mfma<<<gemmGrid, 256, 0, stream>>>(h_bf, agg_bf, ef_bf, DEG, wtm1, c1mb,
                                            nullptr, x1_bf, N, KP_MSG,
                                            F_MSG | F_RELU | F_DEGBIAS | F_OUTB);

    // ---- conv2 ----
    gemm_mfma<<<gemmGrid, 256, 0, stream>>>(x1_bf, nullptr, nullptr, DEG, wtp2, c2pb,
                                            nullptr, h_bf, N, 128, F_RELU | F_OUTB);
    gather_h_bf<<<ghGrid, 256, 0, stream>>>(elist, rowstart, h_bf, agg_bf, N);
    gemm_mfma<<<gemmGrid, 256, 0, stream>>>(h_bf, agg_bf, ef_bf, DEG, wtm2, c2mb,
                                            x2f, nullptr, N, KP_MSG,
                                            F_MSG | F_DEGBIAS | F_OUTF);

    // ---- head ----
    head_kernel<<<headGrid, 256, 0, stream>>>(x2f, eli, lpW, lpb, out, Q);
}